// Round 10
// baseline (40.717 us; speedup 1.0000x reference)
//
#include <hip/hip_runtime.h>
#include <hip/hip_bf16.h>
#include <math.h>

typedef __attribute__((ext_vector_type(8)))  short bf16x8;
typedef __attribute__((ext_vector_type(16))) float f32x16;
typedef unsigned int u32;

#define KAPPA (1.0f/61.0f)
#define NBLK 256           // 128 sample-groups (256 samples) x 2 p-halves
// swap bits 2<->3 of a 5-bit row index (pre-D row -> B-frag k-order fixup)
#define SWAP23(r) (((r) & 19) | (((r) & 4) << 1) | (((r) & 8) >> 1))

__device__ __forceinline__ unsigned short f2bf(float f) {
    u32 x = __float_as_uint(f);
    x += 0x7fffu + ((x >> 16) & 1u);               // RNE
    return (unsigned short)(x >> 16);
}
__device__ __forceinline__ float fast_rcp(float v) {
#if __has_builtin(__builtin_amdgcn_rcpf)
    return __builtin_amdgcn_rcpf(v);
#else
    return 1.0f / v;
#endif
}
__device__ __forceinline__ u32 pack_bf16(float lo, float hi) {
    __hip_bfloat162 p = __float22bfloat162_rn(make_float2(lo, hi));  // v_cvt_pk path
    return *reinterpret_cast<u32*>(&p);
}

// ---------------------------------------------------------------------------
// Kernel 1: precompute MFMA operand fragments (sample-independent).
//  V  frags [16384 lane-frags]: f=(k*8+ptile)*64+lane -> A-frag of V^T:
//       row p = ptile*32+(lane&31), kk h = k*16+(lane>>5)*8+i
//       V[h][p] = W1[l][h]*W2[h][c], p=l*35+c (pad 245->256)
//  Wt frags [1024 lane-frags]: f=htile*64+lane -> A-frag of [W1^T | b1] with
//       SWAP23-permuted rows, so the pre-MFMA's packed D output is directly
//       the main-GEMM B-fragment (verified r9, absmax 0.0).
// ---------------------------------------------------------------------------
__global__ void build_v(const float* __restrict__ W1, const float* __restrict__ W2,
                        const float* __restrict__ b1,
                        bf16x8* __restrict__ V, bf16x8* __restrict__ Wt) {
    int t = blockIdx.x * blockDim.x + threadIdx.x;
    if (t < 16384) {
        int lane = t & 63, ptile = (t >> 6) & 7, kkg = t >> 9;
        int p  = ptile * 32 + (lane & 31);
        int hb = kkg * 16 + (lane >> 5) * 8;
        bool valid = (p < 245);
        int l7 = valid ? p / 35 : 0;
        int c  = valid ? p - l7 * 35 : 0;
        bf16x8 v;
#pragma unroll
        for (int i = 0; i < 8; ++i) {
            int h = hb + i;
            v[i] = valid ? (short)f2bf(W1[l7 * 512 + h] * W2[h * 35 + c]) : (short)0;
        }
        V[t] = v;
    } else if (t < 16384 + 1024) {
        int f = t - 16384;
        int lane = f & 63, htile = f >> 6;
        int row = lane & 31;
        int h = htile * 32 + SWAP23(row);
        bf16x8 v;
#pragma unroll
        for (int i = 0; i < 8; ++i) v[i] = 0;
        if (lane < 32) {
#pragma unroll
            for (int l = 0; l < 7; ++l) v[l] = (short)f2bf(W1[l * 512 + h]);
            v[7] = (short)f2bf(b1[h]);
        }
        Wt[f] = v;
    }
}

// ---------------------------------------------------------------------------
// Kernel 2: main — BARRIER-FREE main loop (waves fully independent).
// 256 blocks x 512 threads (8 waves, 1 block/CU). Block = 256 samples x one
// 128-p half (ph). Wave w = 32 samples (st=w) x all 4 ptiles of the half
// (acc[4] = 64 VGPR). Per 32-h chunk: 1 pre-MFMA (SWAP23 Wt) -> exp/pack ->
// the packed g IS the B-frag -> 8 main MFMAs. ptiles 0..2 of the half come
// from LDS (staged once, ONE barrier); ptile 3 streams from L2 (pipe balance:
// LDS ~2.9us, L2 ~2us, matrix ~3.8us). Per-sample SSQ partial -> global.
// ---------------------------------------------------------------------------
__global__ __launch_bounds__(512, 1)
void torsion_main(const float* __restrict__ x,
                  const bf16x8* __restrict__ V, const bf16x8* __restrict__ Wt,
                  float* __restrict__ partials) {
    __shared__ __align__(16) short Vs[6144 * 8];   // 96 KB: ptiles 0..2 of half

    const int tid  = threadIdx.x;
    const int lane = tid & 63;
    const int w    = tid >> 6;           // 0..7: sample sub-tile
    const int sgrp = blockIdx.x >> 1;    // 0..127: 256-sample group
    const int ph   = blockIdx.x & 1;     // p-half: ptiles ph*4 .. ph*4+3

    // ---- stage V ptiles {ph*4+0,1,2} x 32 ksteps into LDS (coalesced) ----
    {
        bf16x8* vs = reinterpret_cast<bf16x8*>(Vs);
        for (int i = tid; i < 6144; i += 512) {
            int li = i & 63, rest = i >> 6;       // rest = k*3 + pt
            int pt = rest % 3, k = rest / 3;
            vs[i] = V[(k * 8 + ph * 4 + pt) * 64 + li];
        }
    }

    // x B-frag: col = sample, lo half k=0..6 -> x, k=7 -> 1.0; hi half 0
    bf16x8 xf;
#pragma unroll
    for (int i = 0; i < 8; ++i) xf[i] = 0;
    if (lane < 32) {
        const float* xp = x + ((size_t)sgrp * 256 + w * 32 + lane) * 7;
#pragma unroll
        for (int l = 0; l < 7; ++l) xf[l] = (short)f2bf(xp[l]);
        xf[7] = (short)f2bf(1.0f);
    }

    f32x16 acc[4];
#pragma unroll
    for (int pt = 0; pt < 4; ++pt)
#pragma unroll
        for (int e = 0; e < 16; ++e) acc[pt][e] = 0.0f;

    // g from pre-MFMA result: d[0..3]/d[4..7] = B-frags of the 2 ksteps
    auto compute_g2 = [&](const f32x16& p, bf16x8& gA, bf16x8& gB) {
        union { u32 u[4]; bf16x8 v; } ca, cb;
#pragma unroll
        for (int j = 0; j < 8; ++j) {
            float t0 = __expf(-2.0f * fabsf(p[2 * j]));
            float r0 = fast_rcp(1.0f + t0);
            float g0 = 4.0f * t0 * r0 * r0;
            float t1 = __expf(-2.0f * fabsf(p[2 * j + 1]));
            float r1 = fast_rcp(1.0f + t1);
            float g1 = 4.0f * t1 * r1 * r1;
            u32 pk = pack_bf16(g0, g1);
            if (j < 4) ca.u[j] = pk; else cb.u[j - 4] = pk;
        }
        gA = ca.v; gB = cb.v;
    };

    // ---- prologue: pre(0); prefetch pt3 frags of chunk 0 and Wt(1) ----
    bf16x8 wt_next = Wt[1 * 64 + lane];
    bf16x8 v3a = V[(0 * 8 + ph * 4 + 3) * 64 + lane];   // k = 0
    bf16x8 v3b = V[(1 * 8 + ph * 4 + 3) * 64 + lane];   // k = 1
    f32x16 p_cur;
    {
        bf16x8 wt0 = Wt[0 * 64 + lane];
#pragma unroll
        for (int e = 0; e < 16; ++e) p_cur[e] = 0.0f;
        p_cur = __builtin_amdgcn_mfma_f32_32x32x16_bf16(wt0, xf, p_cur, 0, 0, 0);
    }

    __syncthreads();   // Vs ready (the ONLY barrier)

    const bf16x8* vsp = reinterpret_cast<const bf16x8*>(Vs);

#pragma unroll 4
    for (int c = 0; c < 16; ++c) {
        // pre-MFMA for chunk c+1 (matrix pipe; completes during this chunk)
        f32x16 p_next;
        if (c < 15) {
#pragma unroll
            for (int e = 0; e < 16; ++e) p_next[e] = 0.0f;
            p_next = __builtin_amdgcn_mfma_f32_32x32x16_bf16(wt_next, xf, p_next, 0, 0, 0);
        }

        // prefetch next chunk's pt3 frags + Wt(c+2) (L2 latency hidden)
        bf16x8 v3a_n, v3b_n;
        if (c < 15) {
            v3a_n = V[((2 * c + 2) * 8 + ph * 4 + 3) * 64 + lane];
            v3b_n = V[((2 * c + 3) * 8 + ph * 4 + 3) * 64 + lane];
        }
        if (c < 14) wt_next = Wt[(c + 2) * 64 + lane];

        // g for chunk c (depends on p_cur from last iter -> chain hidden)
        bf16x8 g0, g1;
        compute_g2(p_cur, g0, g1);

        // 8 main MFMAs: ks=0 (k=2c), ks=1 (k=2c+1); pt 0..2 LDS, pt3 regs
        const int base0 = (2 * c) * 3 * 64 + lane;
        const int base1 = base0 + 3 * 64;
        acc[0] = __builtin_amdgcn_mfma_f32_32x32x16_bf16(vsp[base0],        g0, acc[0], 0, 0, 0);
        acc[1] = __builtin_amdgcn_mfma_f32_32x32x16_bf16(vsp[base0 + 64],   g0, acc[1], 0, 0, 0);
        acc[2] = __builtin_amdgcn_mfma_f32_32x32x16_bf16(vsp[base0 + 128],  g0, acc[2], 0, 0, 0);
        acc[3] = __builtin_amdgcn_mfma_f32_32x32x16_bf16(v3a,               g0, acc[3], 0, 0, 0);
        acc[0] = __builtin_amdgcn_mfma_f32_32x32x16_bf16(vsp[base1],        g1, acc[0], 0, 0, 0);
        acc[1] = __builtin_amdgcn_mfma_f32_32x32x16_bf16(vsp[base1 + 64],   g1, acc[1], 0, 0, 0);
        acc[2] = __builtin_amdgcn_mfma_f32_32x32x16_bf16(vsp[base1 + 128],  g1, acc[2], 0, 0, 0);
        acc[3] = __builtin_amdgcn_mfma_f32_32x32x16_bf16(v3b,               g1, acc[3], 0, 0, 0);

        // rotate pipeline regs (SSA: no real moves after unroll)
        p_cur = p_next;
        v3a = v3a_n;
        v3b = v3b_n;
    }

    // ---- epilogue: per-sample partial SSQ over this p-half ----
    // D[p][sample]: col = lane&31 = sample; lane^32 holds the other 16 p-rows.
    {
        float s = 0.0f;
#pragma unroll
        for (int pt = 0; pt < 4; ++pt)
#pragma unroll
            for (int e = 0; e < 16; ++e) s += acc[pt][e] * acc[pt][e];
        s += __shfl_xor(s, 32);
        if (lane < 32)
            partials[(size_t)ph * 32768 + sgrp * 256 + w * 32 + lane] = s;
    }
}

// ---------------------------------------------------------------------------
// Kernel 3: finalize — per-sample sqrt + deterministic mean (1 block).
// ---------------------------------------------------------------------------
__global__ __launch_bounds__(1024)
void finalize_k(const float* __restrict__ partials, float* __restrict__ out) {
    __shared__ float sl[1024], sn[1024];
    const int tid = threadIdx.x;
    float a = 0.0f, b = 0.0f;
    for (int s = tid; s < 32768; s += 1024) {
        float q = 6.0f * (partials[s] + partials[32768 + s]);
        float n = sqrtf(q + 1e-10f);
        float dd = n - KAPPA;
        a += dd * dd;
        b += n;
    }
    sl[tid] = a; sn[tid] = b;
    __syncthreads();
    for (int st = 512; st > 0; st >>= 1) {
        if (tid < st) { sl[tid] += sl[tid + st]; sn[tid] += sn[tid + st]; }
        __syncthreads();
    }
    if (tid == 0) {
        out[0] = sl[0] / 32768.0f;
        out[1] = sn[0] / 32768.0f;
    }
}

// ---------------------------------------------------------------------------
extern "C" void kernel_launch(void* const* d_in, const int* in_sizes, int n_in,
                              void* d_out, int out_size, void* d_ws, size_t ws_size,
                              hipStream_t stream) {
    const float* x  = (const float*)d_in[0];
    const float* W1 = (const float*)d_in[1];
    const float* b1 = (const float*)d_in[2];
    const float* W2 = (const float*)d_in[3];
    // b2 (d_in[4]) unused: the Jacobian kills the bias.

    bf16x8* V        = (bf16x8*)d_ws;          // 16384 lane-frags * 16 B = 256 KB
    bf16x8* Wt       = V + 16384;              // 1024 lane-frags * 16 B = 16 KB
    float*  partials = (float*)(Wt + 1024);    // 2 * 32768 floats = 256 KB

    build_v<<<68, 256, 0, stream>>>(W1, W2, b1, V, Wt);
    torsion_main<<<NBLK, 512, 0, stream>>>(x, V, Wt, partials);
    finalize_k<<<1, 1024, 0, stream>>>(partials, (float*)d_out);
}

// Round 11
// 31.991 us; speedup vs baseline: 1.2728x; 1.2728x over previous
//
#include <hip/hip_runtime.h>
#include <hip/hip_bf16.h>
#include <math.h>

typedef __attribute__((ext_vector_type(8)))  short bf16x8;
typedef __attribute__((ext_vector_type(16))) float f32x16;
typedef unsigned int u32;

#define KAPPA (1.0f/61.0f)
#define NBLK 512           // 32768 rows / 64 rows-per-block
// swap bits 2<->3 of a 5-bit row index (pre-D row -> B-frag k-order fixup)
#define SWAP23(r) (((r) & 19) | (((r) & 4) << 1) | (((r) & 8) >> 1))

__device__ __forceinline__ unsigned short f2bf(float f) {
    u32 x = __float_as_uint(f);
    x += 0x7fffu + ((x >> 16) & 1u);               // RNE
    return (unsigned short)(x >> 16);
}
__device__ __forceinline__ float fast_rcp(float v) {
#if __has_builtin(__builtin_amdgcn_rcpf)
    return __builtin_amdgcn_rcpf(v);
#else
    return 1.0f / v;
#endif
}
__device__ __forceinline__ u32 pack_bf16(float lo, float hi) {
    __hip_bfloat162 p = __float22bfloat162_rn(make_float2(lo, hi));  // v_cvt_pk path
    return *reinterpret_cast<u32*>(&p);
}

// ---------------------------------------------------------------------------
// Kernel 1: precompute MFMA operand fragments (sample-independent) + zero the
// finalize ticket.
//  V  frags [16384]: f=(kkg*8+ptile)*64+lane -> A-frag of V^T:
//       row p = ptile*32+(lane&31), k h = kkg*16+(lane>>5)*8+i
//       V[h][p] = W1[l][h]*W2[h][c], p=l*35+c (pad 245->256)
//  Wt frags [1024]: f=htile*64+lane -> A-frag of [W1^T | b1] with SWAP23-
//       permuted rows (row r -> h = htile*32 + SWAP23(r)), so the pre-MFMA's
//       packed D output is directly the main-GEMM B-fragment (verified r9).
// ---------------------------------------------------------------------------
__global__ void build_v(const float* __restrict__ W1, const float* __restrict__ W2,
                        const float* __restrict__ b1,
                        bf16x8* __restrict__ V, bf16x8* __restrict__ Wt,
                        int* __restrict__ ticket) {
    int t = blockIdx.x * blockDim.x + threadIdx.x;
    if (t == 0) *ticket = 0;                       // re-zeroed every launch
    if (t < 16384) {
        int lane = t & 63, ptile = (t >> 6) & 7, kkg = t >> 9;
        int p  = ptile * 32 + (lane & 31);
        int hb = kkg * 16 + (lane >> 5) * 8;
        bool valid = (p < 245);
        int l7 = valid ? p / 35 : 0;
        int c  = valid ? p - l7 * 35 : 0;
        bf16x8 v;
#pragma unroll
        for (int i = 0; i < 8; ++i) {
            int h = hb + i;
            v[i] = valid ? (short)f2bf(W1[l7 * 512 + h] * W2[h * 35 + c]) : (short)0;
        }
        V[t] = v;
    } else if (t < 16384 + 1024) {
        int f = t - 16384;
        int lane = f & 63, htile = f >> 6;
        int row = lane & 31;
        int h = htile * 32 + SWAP23(row);
        bf16x8 v;
#pragma unroll
        for (int i = 0; i < 8; ++i) v[i] = 0;
        if (lane < 32) {
#pragma unroll
            for (int l = 0; l < 7; ++l) v[l] = (short)f2bf(W1[l * 512 + h]);
            v[7] = (short)f2bf(b1[h]);
        }
        Wt[f] = v;
    }
}

// ---------------------------------------------------------------------------
// Kernel 2: main (r7 champion structure + SWAP23 B-frag stores + early store_g
// + fused last-block finalize).
// 512 blocks x 256 threads (4 waves); block = 64 samples x 256 p. Wave w:
// phase A pre-tile (ht=w>>1, rt=w&1); phase B ptiles {2w,2w+1} x both sample
// tiles (acc[2][2] = 64 VGPR). Chunk = 64 h, double-buffered G, one barrier
// per chunk. Per chunk: (1) batch-issue 8 V-frag loads, (2) pre_pack(c+1)
// trans chain hides V latency, (3) publish G(c+1) (buf^1: race-free),
// (4) 16-MFMA cluster. Last block to finish reduces the 512 partials.
// ---------------------------------------------------------------------------
__global__ __launch_bounds__(256, 3)
void torsion_main(const float* __restrict__ x,
                  const bf16x8* __restrict__ V, const bf16x8* __restrict__ Wt,
                  float* __restrict__ partials, int* __restrict__ ticket,
                  float* __restrict__ out) {
    __shared__ __align__(16) u32 Gb[2][8][64 * 4];   // [buf][ks*2+rt][lane dwords] = 16KB
    __shared__ float red[4][2][32];
    __shared__ int is_last;

    const int tid  = threadIdx.x;
    const int lane = tid & 63;
    const int w    = tid >> 6;
    const int blk  = blockIdx.x;
    const int rt   = w & 1;      // sample tile this wave's pre covers
    const int ht   = w >> 1;     // h-subtile (0..1) within chunk

    // x B-frag (once): col = sample, lo half k=0..6 -> x, k=7 -> 1.0; hi half 0
    bf16x8 xf;
#pragma unroll
    for (int i = 0; i < 8; ++i) xf[i] = 0;
    if (lane < 32) {
        const float* xp = x + ((size_t)blk * 64 + rt * 32 + lane) * 7;
#pragma unroll
        for (int l = 0; l < 7; ++l) xf[l] = (short)f2bf(xp[l]);
        xf[7] = (short)f2bf(1.0f);
    }

    f32x16 acc[2][2];
#pragma unroll
    for (int pt = 0; pt < 2; ++pt)
#pragma unroll
        for (int r2 = 0; r2 < 2; ++r2)
#pragma unroll
            for (int e = 0; e < 16; ++e) acc[pt][r2][e] = 0.0f;

    // pre^T tile for chunk c -> 8 packed dwords of g. With SWAP23-permuted Wt,
    // d[0..3] IS the B-frag for kstep 2ht, d[4..7] for kstep 2ht+1.
    auto pre_pack = [&](int c, u32 d[8]) {
        bf16x8 wf = Wt[(c * 2 + ht) * 64 + lane];
        f32x16 p;
#pragma unroll
        for (int e = 0; e < 16; ++e) p[e] = 0.0f;
        p = __builtin_amdgcn_mfma_f32_32x32x16_bf16(wf, xf, p, 0, 0, 0);
#pragma unroll
        for (int j = 0; j < 8; ++j) {
            float t0 = __expf(-2.0f * fabsf(p[2 * j]));
            float r0 = fast_rcp(1.0f + t0);
            float g0 = 4.0f * t0 * r0 * r0;
            float t1 = __expf(-2.0f * fabsf(p[2 * j + 1]));
            float r1 = fast_rcp(1.0f + t1);
            float g1 = 4.0f * t1 * r1 * r1;
            d[j] = pack_bf16(g0, g1);
        }
    };
    // store: two ds_write_b128, no scatter (d is already B-frag register data)
    auto store_g = [&](int buf, const u32 d[8]) {
        *reinterpret_cast<uint4*>(&Gb[buf][(2 * ht + 0) * 2 + rt][lane * 4]) =
            make_uint4(d[0], d[1], d[2], d[3]);
        *reinterpret_cast<uint4*>(&Gb[buf][(2 * ht + 1) * 2 + rt][lane * 4]) =
            make_uint4(d[4], d[5], d[6], d[7]);
    };

    {
        u32 d0[8];
        pre_pack(0, d0);
        store_g(0, d0);
    }
    __syncthreads();

    for (int c = 0; c < 8; ++c) {
        const int buf = c & 1;

        // (1) issue ALL this chunk's V loads back-to-back (8 dwordx4 in flight)
        bf16x8 vreg[8];
#pragma unroll
        for (int ks = 0; ks < 4; ++ks) {
            const int fb = ((c * 4 + ks) * 8 + 2 * w) * 64 + lane;
            vreg[2 * ks]     = V[fb];
            vreg[2 * ks + 1] = V[fb + 64];
        }

        // (2) next chunk's pre: trans chain hides V latency
        u32 dn[8];
        if (c < 7) pre_pack(c + 1, dn);

        // (3) publish next chunk's G early (writes buf^1, reads are from buf)
        if (c < 7) store_g(buf ^ 1, dn);

        // (4) MFMA cluster
        __builtin_amdgcn_s_setprio(1);
#pragma unroll
        for (int ks = 0; ks < 4; ++ks) {
            bf16x8 g0 = *reinterpret_cast<const bf16x8*>(&Gb[buf][ks * 2 + 0][lane * 4]);
            bf16x8 g1 = *reinterpret_cast<const bf16x8*>(&Gb[buf][ks * 2 + 1][lane * 4]);
            acc[0][0] = __builtin_amdgcn_mfma_f32_32x32x16_bf16(vreg[2 * ks],     g0, acc[0][0], 0, 0, 0);
            acc[0][1] = __builtin_amdgcn_mfma_f32_32x32x16_bf16(vreg[2 * ks],     g1, acc[0][1], 0, 0, 0);
            acc[1][0] = __builtin_amdgcn_mfma_f32_32x32x16_bf16(vreg[2 * ks + 1], g0, acc[1][0], 0, 0, 0);
            acc[1][1] = __builtin_amdgcn_mfma_f32_32x32x16_bf16(vreg[2 * ks + 1], g1, acc[1][1], 0, 0, 0);
        }
        __builtin_amdgcn_s_setprio(0);
        __syncthreads();
    }

    // ---- epilogue: D[p][sample]: col = sample; lane & lane^32 share a sample.
#pragma unroll
    for (int r2 = 0; r2 < 2; ++r2) {
        float s = 0.0f;
#pragma unroll
        for (int pt = 0; pt < 2; ++pt)
#pragma unroll
            for (int e = 0; e < 16; ++e) s += acc[pt][r2][e] * acc[pt][r2][e];
        s += __shfl_xor(s, 32);
        if (lane < 32) red[w][r2][lane] = s;
    }
    __syncthreads();

    if (tid < 64) {
        const int li = tid & 31, rr = tid >> 5;
        float q = 6.0f * (red[0][rr][li] + red[1][rr][li] + red[2][rr][li] + red[3][rr][li]);
        float n = sqrtf(q + 1e-10f);
        float d = n - KAPPA;
        float a = d * d, b = n;
#pragma unroll
        for (int m = 1; m <= 32; m <<= 1) {
            a += __shfl_xor(a, m);
            b += __shfl_xor(b, m);
        }
        if (tid == 0) {
            partials[blk]        = a;
            partials[NBLK + blk] = b;
        }
    }
    __syncthreads();

    // ---- fused finalize: last block to arrive reduces all 512 partials ----
    if (tid == 0) {
        __threadfence();                       // partials visible device-wide
        int old = atomicAdd(ticket, 1);
        is_last = (old == NBLK - 1) ? 1 : 0;
    }
    __syncthreads();
    if (is_last && tid < 64) {
        __threadfence();                       // acquire other blocks' partials
        float a = 0.0f, b = 0.0f;
#pragma unroll
        for (int i = 0; i < NBLK / 64; ++i) {  // fixed order -> deterministic
            a += partials[i * 64 + tid];
            b += partials[NBLK + i * 64 + tid];
        }
#pragma unroll
        for (int m = 1; m <= 32; m <<= 1) {
            a += __shfl_xor(a, m);
            b += __shfl_xor(b, m);
        }
        if (tid == 0) {
            out[0] = a / 32768.0f;
            out[1] = b / 32768.0f;
        }
    }
}

// ---------------------------------------------------------------------------
extern "C" void kernel_launch(void* const* d_in, const int* in_sizes, int n_in,
                              void* d_out, int out_size, void* d_ws, size_t ws_size,
                              hipStream_t stream) {
    const float* x  = (const float*)d_in[0];
    const float* W1 = (const float*)d_in[1];
    const float* b1 = (const float*)d_in[2];
    const float* W2 = (const float*)d_in[3];
    // b2 (d_in[4]) unused: the Jacobian kills the bias.

    bf16x8* V        = (bf16x8*)d_ws;          // 16384 frags * 16 B = 256 KB
    bf16x8* Wt       = V + 16384;              // 1024 frags * 16 B = 16 KB
    float*  partials = (float*)(Wt + 1024);    // 1024 floats
    int*    ticket   = (int*)(partials + 2 * NBLK);

    build_v<<<68, 256, 0, stream>>>(W1, W2, b1, V, Wt, ticket);
    torsion_main<<<NBLK, 256, 0, stream>>>(x, V, Wt, partials, ticket, (float*)d_out);
}

// Round 12
// 25.483 us; speedup vs baseline: 1.5978x; 1.2554x over previous
//
#include <hip/hip_runtime.h>
#include <hip/hip_bf16.h>
#include <math.h>

typedef __attribute__((ext_vector_type(8)))  short bf16x8;
typedef __attribute__((ext_vector_type(16))) float f32x16;
typedef unsigned int u32;

#define KAPPA (1.0f/61.0f)
#define NBLK 512           // 32768 rows / 64 rows-per-block
// swap bits 2<->3 of a 5-bit row index (pre-D row -> B-frag k-order fixup)
#define SWAP23(r) (((r) & 19) | (((r) & 4) << 1) | (((r) & 8) >> 1))

__device__ __forceinline__ unsigned short f2bf(float f) {
    u32 x = __float_as_uint(f);
    x += 0x7fffu + ((x >> 16) & 1u);               // RNE
    return (unsigned short)(x >> 16);
}
__device__ __forceinline__ float fast_rcp(float v) {
#if __has_builtin(__builtin_amdgcn_rcpf)
    return __builtin_amdgcn_rcpf(v);
#else
    return 1.0f / v;
#endif
}
__device__ __forceinline__ u32 pack_bf16(float lo, float hi) {
    __hip_bfloat162 p = __float22bfloat162_rn(make_float2(lo, hi));  // v_cvt_pk path
    return *reinterpret_cast<u32*>(&p);
}

// ---------------------------------------------------------------------------
// Kernel 1: precompute MFMA operand fragments (all sample-independent).
//  V  frags [16384]: f=(kkg*8+ptile)*64+lane -> A-frag of V^T:
//       row p = ptile*32+(lane&31), k h = kkg*16+(lane>>5)*8+i
//       V[h][p] = W1[l][h]*W2[h][c], p=l*35+c (pad 245->256)
//  Wt frags [1024]: f=htile*64+lane -> A-frag of [W1^T | b1] with SWAP23-
//       permuted rows (row r -> h = htile*32 + SWAP23(r)), so the pre-MFMA's
//       packed D output is directly the main-GEMM B-fragment (verified r9).
// ---------------------------------------------------------------------------
__global__ void build_v(const float* __restrict__ W1, const float* __restrict__ W2,
                        const float* __restrict__ b1,
                        bf16x8* __restrict__ V, bf16x8* __restrict__ Wt) {
    int t = blockIdx.x * blockDim.x + threadIdx.x;
    if (t < 16384) {
        int lane = t & 63, ptile = (t >> 6) & 7, kkg = t >> 9;
        int p  = ptile * 32 + (lane & 31);
        int hb = kkg * 16 + (lane >> 5) * 8;
        bool valid = (p < 245);
        int l7 = valid ? p / 35 : 0;
        int c  = valid ? p - l7 * 35 : 0;
        bf16x8 v;
#pragma unroll
        for (int i = 0; i < 8; ++i) {
            int h = hb + i;
            v[i] = valid ? (short)f2bf(W1[l7 * 512 + h] * W2[h * 35 + c]) : (short)0;
        }
        V[t] = v;
    } else if (t < 16384 + 1024) {
        int f = t - 16384;
        int lane = f & 63, htile = f >> 6;
        int row = lane & 31;
        int h = htile * 32 + SWAP23(row);
        bf16x8 v;
#pragma unroll
        for (int i = 0; i < 8; ++i) v[i] = 0;
        if (lane < 32) {
#pragma unroll
            for (int l = 0; l < 7; ++l) v[l] = (short)f2bf(W1[l * 512 + h]);
            v[7] = (short)f2bf(b1[h]);
        }
        Wt[f] = v;
    }
}

// ---------------------------------------------------------------------------
// Kernel 2: main — r7 champion structure, byte-for-byte ordering, with the
// single change that store_g is two contiguous ds_write_b128 (SWAP23 makes
// the packed pre output directly the B-frag; no b64 scatter, no shuffles).
// 512 blocks x 256 threads (4 waves); block = 64 samples x 256 p. Wave w:
// phase A pre-tile (ht=w>>1, rt=w&1); phase B ptiles {2w,2w+1} x both sample
// tiles (acc[2][2] = 64 VGPR). Chunk = 64 h, double-buffered G, one barrier
// per chunk. Order per chunk: (1) batch-issue 8 V loads, (2) pre_pack(c+1)
// hides V latency, (3) MFMA cluster (reads first!), (4) store_g, barrier.
// ---------------------------------------------------------------------------
__global__ __launch_bounds__(256, 3)
void torsion_main(const float* __restrict__ x,
                  const bf16x8* __restrict__ V, const bf16x8* __restrict__ Wt,
                  float* __restrict__ partials) {
    __shared__ __align__(16) u32 Gb[2][8][64 * 4];   // [buf][ks*2+rt][lane dwords] = 16KB
    __shared__ float red[4][2][32];

    const int tid  = threadIdx.x;
    const int lane = tid & 63;
    const int w    = tid >> 6;
    const int blk  = blockIdx.x;
    const int rt   = w & 1;      // sample tile this wave's pre covers
    const int ht   = w >> 1;     // h-subtile (0..1) within chunk

    // x B-frag (once): col = sample, lo half k=0..6 -> x, k=7 -> 1.0; hi half 0
    bf16x8 xf;
#pragma unroll
    for (int i = 0; i < 8; ++i) xf[i] = 0;
    if (lane < 32) {
        const float* xp = x + ((size_t)blk * 64 + rt * 32 + lane) * 7;
#pragma unroll
        for (int l = 0; l < 7; ++l) xf[l] = (short)f2bf(xp[l]);
        xf[7] = (short)f2bf(1.0f);
    }

    f32x16 acc[2][2];
#pragma unroll
    for (int pt = 0; pt < 2; ++pt)
#pragma unroll
        for (int r2 = 0; r2 < 2; ++r2)
#pragma unroll
            for (int e = 0; e < 16; ++e) acc[pt][r2][e] = 0.0f;

    // pre^T tile for chunk c -> 8 packed dwords of g. With SWAP23-permuted Wt,
    // d[0..3] IS the B-frag for kstep 2ht, d[4..7] for kstep 2ht+1.
    auto pre_pack = [&](int c, u32 d[8]) {
        bf16x8 wf = Wt[(c * 2 + ht) * 64 + lane];
        f32x16 p;
#pragma unroll
        for (int e = 0; e < 16; ++e) p[e] = 0.0f;
        p = __builtin_amdgcn_mfma_f32_32x32x16_bf16(wf, xf, p, 0, 0, 0);
#pragma unroll
        for (int j = 0; j < 8; ++j) {
            float t0 = __expf(-2.0f * fabsf(p[2 * j]));
            float r0 = fast_rcp(1.0f + t0);
            float g0 = 4.0f * t0 * r0 * r0;
            float t1 = __expf(-2.0f * fabsf(p[2 * j + 1]));
            float r1 = fast_rcp(1.0f + t1);
            float g1 = 4.0f * t1 * r1 * r1;
            d[j] = pack_bf16(g0, g1);
        }
    };
    // store: two contiguous conflict-free ds_write_b128 (no scatter)
    auto store_g = [&](int buf, const u32 d[8]) {
        *reinterpret_cast<uint4*>(&Gb[buf][(2 * ht + 0) * 2 + rt][lane * 4]) =
            make_uint4(d[0], d[1], d[2], d[3]);
        *reinterpret_cast<uint4*>(&Gb[buf][(2 * ht + 1) * 2 + rt][lane * 4]) =
            make_uint4(d[4], d[5], d[6], d[7]);
    };

    {
        u32 d0[8];
        pre_pack(0, d0);
        store_g(0, d0);
    }
    __syncthreads();

    for (int c = 0; c < 8; ++c) {
        const int buf = c & 1;

        // (1) issue ALL this chunk's V loads back-to-back (8 dwordx4 in flight)
        bf16x8 vreg[8];
#pragma unroll
        for (int ks = 0; ks < 4; ++ks) {
            const int fb = ((c * 4 + ks) * 8 + 2 * w) * 64 + lane;
            vreg[2 * ks]     = V[fb];
            vreg[2 * ks + 1] = V[fb + 64];
        }

        // (2) next chunk's pre: trans chain hides V latency
        u32 dn[8];
        if (c < 7) pre_pack(c + 1, dn);

        // (3) MFMA cluster (LDS reads issue before any new LDS writes)
        __builtin_amdgcn_s_setprio(1);
#pragma unroll
        for (int ks = 0; ks < 4; ++ks) {
            bf16x8 g0 = *reinterpret_cast<const bf16x8*>(&Gb[buf][ks * 2 + 0][lane * 4]);
            bf16x8 g1 = *reinterpret_cast<const bf16x8*>(&Gb[buf][ks * 2 + 1][lane * 4]);
            acc[0][0] = __builtin_amdgcn_mfma_f32_32x32x16_bf16(vreg[2 * ks],     g0, acc[0][0], 0, 0, 0);
            acc[0][1] = __builtin_amdgcn_mfma_f32_32x32x16_bf16(vreg[2 * ks],     g1, acc[0][1], 0, 0, 0);
            acc[1][0] = __builtin_amdgcn_mfma_f32_32x32x16_bf16(vreg[2 * ks + 1], g0, acc[1][0], 0, 0, 0);
            acc[1][1] = __builtin_amdgcn_mfma_f32_32x32x16_bf16(vreg[2 * ks + 1], g1, acc[1][1], 0, 0, 0);
        }
        __builtin_amdgcn_s_setprio(0);

        // (4) publish next chunk's G, then barrier (writes drain in barrier)
        if (c < 7) store_g(buf ^ 1, dn);
        __syncthreads();
    }

    // ---- epilogue: D[p][sample]: col = sample; lane & lane^32 share a sample.
#pragma unroll
    for (int r2 = 0; r2 < 2; ++r2) {
        float s = 0.0f;
#pragma unroll
        for (int pt = 0; pt < 2; ++pt)
#pragma unroll
            for (int e = 0; e < 16; ++e) s += acc[pt][r2][e] * acc[pt][r2][e];
        s += __shfl_xor(s, 32);
        if (lane < 32) red[w][r2][lane] = s;
    }
    __syncthreads();

    if (tid < 64) {
        const int li = tid & 31, rr = tid >> 5;
        float q = 6.0f * (red[0][rr][li] + red[1][rr][li] + red[2][rr][li] + red[3][rr][li]);
        float n = sqrtf(q + 1e-10f);
        float d = n - KAPPA;
        float a = d * d, b = n;
#pragma unroll
        for (int m = 1; m <= 32; m <<= 1) {
            a += __shfl_xor(a, m);
            b += __shfl_xor(b, m);
        }
        if (tid == 0) {
            partials[blk]        = a;
            partials[NBLK + blk] = b;
        }
    }
}

// ---------------------------------------------------------------------------
// Kernel 3: finalize — deterministic sum of 512 per-block partials.
// ---------------------------------------------------------------------------
__global__ void finalize_k(const float* __restrict__ partials, float* __restrict__ out) {
    __shared__ float sl[256], sn[256];
    int tid = threadIdx.x;
    sl[tid] = partials[tid] + partials[tid + 256];
    sn[tid] = partials[NBLK + tid] + partials[NBLK + tid + 256];
    __syncthreads();
    for (int st = 128; st > 0; st >>= 1) {
        if (tid < st) { sl[tid] += sl[tid + st]; sn[tid] += sn[tid + st]; }
        __syncthreads();
    }
    if (tid == 0) {
        out[0] = sl[0] / 32768.0f;
        out[1] = sn[0] / 32768.0f;
    }
}

// ---------------------------------------------------------------------------
extern "C" void kernel_launch(void* const* d_in, const int* in_sizes, int n_in,
                              void* d_out, int out_size, void* d_ws, size_t ws_size,
                              hipStream_t stream) {
    const float* x  = (const float*)d_in[0];
    const float* W1 = (const float*)d_in[1];
    const float* b1 = (const float*)d_in[2];
    const float* W2 = (const float*)d_in[3];
    // b2 (d_in[4]) unused: the Jacobian kills the bias.

    bf16x8* V        = (bf16x8*)d_ws;          // 16384 frags * 16 B = 256 KB
    bf16x8* Wt       = V + 16384;              // 1024 frags * 16 B = 16 KB
    float*  partials = (float*)(Wt + 1024);    // 1024 floats

    build_v<<<68, 256, 0, stream>>>(W1, W2, b1, V, Wt);
    torsion_main<<<NBLK, 256, 0, stream>>>(x, V, Wt, partials);
    finalize_k<<<1, 256, 0, stream>>>(partials, (float*)d_out);
}

// Round 13
// 24.607 us; speedup vs baseline: 1.6547x; 1.0356x over previous
//
#include <hip/hip_runtime.h>
#include <hip/hip_bf16.h>
#include <math.h>

typedef __attribute__((ext_vector_type(8)))  short bf16x8;
typedef __attribute__((ext_vector_type(16))) float f32x16;
typedef unsigned int u32;

#define KAPPA (1.0f/61.0f)
#define NBLK 512           // 32768 rows / 64 rows-per-block
// swap bits 2<->3 of a 5-bit row index (pre-D row -> B-frag k-order fixup)
#define SWAP23(r) (((r) & 19) | (((r) & 4) << 1) | (((r) & 8) >> 1))

__device__ __forceinline__ unsigned short f2bf(float f) {
    u32 x = __float_as_uint(f);
    x += 0x7fffu + ((x >> 16) & 1u);               // RNE
    return (unsigned short)(x >> 16);
}
__device__ __forceinline__ float fast_rcp(float v) {
#if __has_builtin(__builtin_amdgcn_rcpf)
    return __builtin_amdgcn_rcpf(v);
#else
    return 1.0f / v;
#endif
}
__device__ __forceinline__ float exp2_fast(float v) {
#if __has_builtin(__builtin_amdgcn_exp2f)
    return __builtin_amdgcn_exp2f(v);              // raw v_exp_f32
#else
    return exp2f(v);
#endif
}
__device__ __forceinline__ u32 pack_bf16(float lo, float hi) {
    __hip_bfloat162 p = __float22bfloat162_rn(make_float2(lo, hi));  // v_cvt_pk path
    return *reinterpret_cast<u32*>(&p);
}

// ---------------------------------------------------------------------------
// Kernel 1: precompute MFMA operand fragments (all sample-independent).
//  V  frags [16384]: f=(kkg*8+ptile)*64+lane -> A-frag of 4*V^T:
//       row p = ptile*32+(lane&31), k h = kkg*16+(lane>>5)*8+i
//       V[h][p] = 4 * W1[l][h]*W2[h][c], p=l*35+c (pad 245->256).
//       The 4 is the folded constant from g = 4*t*r^2 (J invariant).
//  Wt frags [1024]: f=htile*64+lane -> A-frag of [W1^T | b1] with SWAP23-
//       permuted rows (row r -> h = htile*32 + SWAP23(r)), so the pre-MFMA's
//       packed D output is directly the main-GEMM B-fragment (verified r9).
// ---------------------------------------------------------------------------
__global__ void build_v(const float* __restrict__ W1, const float* __restrict__ W2,
                        const float* __restrict__ b1,
                        bf16x8* __restrict__ V, bf16x8* __restrict__ Wt) {
    int t = blockIdx.x * blockDim.x + threadIdx.x;
    if (t < 16384) {
        int lane = t & 63, ptile = (t >> 6) & 7, kkg = t >> 9;
        int p  = ptile * 32 + (lane & 31);
        int hb = kkg * 16 + (lane >> 5) * 8;
        bool valid = (p < 245);
        int l7 = valid ? p / 35 : 0;
        int c  = valid ? p - l7 * 35 : 0;
        bf16x8 v;
#pragma unroll
        for (int i = 0; i < 8; ++i) {
            int h = hb + i;
            v[i] = valid ? (short)f2bf(4.0f * W1[l7 * 512 + h] * W2[h * 35 + c]) : (short)0;
        }
        V[t] = v;
    } else if (t < 16384 + 1024) {
        int f = t - 16384;
        int lane = f & 63, htile = f >> 6;
        int row = lane & 31;
        int h = htile * 32 + SWAP23(row);
        bf16x8 v;
#pragma unroll
        for (int i = 0; i < 8; ++i) v[i] = 0;
        if (lane < 32) {
#pragma unroll
            for (int l = 0; l < 7; ++l) v[l] = (short)f2bf(W1[l * 512 + h]);
            v[7] = (short)f2bf(b1[h]);
        }
        Wt[f] = v;
    }
}

// ---------------------------------------------------------------------------
// Kernel 2: main — r12 champion structure with a shortened per-chunk serial
// chain: Wt is register-prefetched one chunk ahead (pre-MFMA issues with no
// memory wait), and g = t*r^2 with t = 2^(-2.8853901*|pre|) (the 4 folded
// into V, the 1/ln2 folded into one abs-modified mul).
// 512 blocks x 256 threads (4 waves); block = 64 samples x 256 p. Wave w:
// phase A pre-tile (ht=w>>1, rt=w&1); phase B ptiles {2w,2w+1} x both sample
// tiles (acc[2][2] = 64 VGPR). Chunk = 64 h, double-buffered G, one barrier
// per chunk. Order per chunk: (1) batch-issue 8 V loads + next Wt load,
// (2) pre_pack(c+1) from prefetched wfn, (3) MFMA cluster, (4) store_g, barrier.
// ---------------------------------------------------------------------------
__global__ __launch_bounds__(256, 3)
void torsion_main(const float* __restrict__ x,
                  const bf16x8* __restrict__ V, const bf16x8* __restrict__ Wt,
                  float* __restrict__ partials) {
    __shared__ __align__(16) u32 Gb[2][8][64 * 4];   // [buf][ks*2+rt][lane dwords] = 16KB
    __shared__ float red[4][2][32];

    const int tid  = threadIdx.x;
    const int lane = tid & 63;
    const int w    = tid >> 6;
    const int blk  = blockIdx.x;
    const int rt   = w & 1;      // sample tile this wave's pre covers
    const int ht   = w >> 1;     // h-subtile (0..1) within chunk

    // x B-frag (once): col = sample, lo half k=0..6 -> x, k=7 -> 1.0; hi half 0
    bf16x8 xf;
#pragma unroll
    for (int i = 0; i < 8; ++i) xf[i] = 0;
    if (lane < 32) {
        const float* xp = x + ((size_t)blk * 64 + rt * 32 + lane) * 7;
#pragma unroll
        for (int l = 0; l < 7; ++l) xf[l] = (short)f2bf(xp[l]);
        xf[7] = (short)f2bf(1.0f);
    }

    f32x16 acc[2][2];
#pragma unroll
    for (int pt = 0; pt < 2; ++pt)
#pragma unroll
        for (int r2 = 0; r2 < 2; ++r2)
#pragma unroll
            for (int e = 0; e < 16; ++e) acc[pt][r2][e] = 0.0f;

    // pre^T tile -> 8 packed dwords of g (wf passed in, prefetched).
    // With SWAP23-permuted Wt, d[0..3] IS the B-frag for kstep 2ht,
    // d[4..7] for kstep 2ht+1. g = t*r^2 (the 4 lives in V).
    auto pre_pack = [&](bf16x8 wf, u32 d[8]) {
        f32x16 p;
#pragma unroll
        for (int e = 0; e < 16; ++e) p[e] = 0.0f;
        p = __builtin_amdgcn_mfma_f32_32x32x16_bf16(wf, xf, p, 0, 0, 0);
#pragma unroll
        for (int j = 0; j < 8; ++j) {
            float t0 = exp2_fast(-2.8853901f * fabsf(p[2 * j]));
            float r0 = fast_rcp(1.0f + t0);
            float g0 = t0 * r0 * r0;
            float t1 = exp2_fast(-2.8853901f * fabsf(p[2 * j + 1]));
            float r1 = fast_rcp(1.0f + t1);
            float g1 = t1 * r1 * r1;
            d[j] = pack_bf16(g0, g1);
        }
    };
    // store: two contiguous conflict-free ds_write_b128 (no scatter)
    auto store_g = [&](int buf, const u32 d[8]) {
        *reinterpret_cast<uint4*>(&Gb[buf][(2 * ht + 0) * 2 + rt][lane * 4]) =
            make_uint4(d[0], d[1], d[2], d[3]);
        *reinterpret_cast<uint4*>(&Gb[buf][(2 * ht + 1) * 2 + rt][lane * 4]) =
            make_uint4(d[4], d[5], d[6], d[7]);
    };

    // prologue: chunk-0 pre from Wt(0); prefetch Wt(1) into wfn
    bf16x8 wfn;
    {
        bf16x8 wf0 = Wt[(0 * 2 + ht) * 64 + lane];
        wfn = Wt[(1 * 2 + ht) * 64 + lane];
        u32 d0[8];
        pre_pack(wf0, d0);
        store_g(0, d0);
    }
    __syncthreads();

    for (int c = 0; c < 8; ++c) {
        const int buf = c & 1;

        // (1) issue ALL this chunk's V loads back-to-back + Wt(c+2) prefetch
        bf16x8 vreg[8];
#pragma unroll
        for (int ks = 0; ks < 4; ++ks) {
            const int fb = ((c * 4 + ks) * 8 + 2 * w) * 64 + lane;
            vreg[2 * ks]     = V[fb];
            vreg[2 * ks + 1] = V[fb + 64];
        }
        bf16x8 wf2;
        if (c < 6) wf2 = Wt[((c + 2) * 2 + ht) * 64 + lane];

        // (2) next chunk's pre from PREFETCHED wfn: MFMA issues immediately,
        //     exp chain + V-load latency overlap
        u32 dn[8];
        if (c < 7) pre_pack(wfn, dn);

        // (3) MFMA cluster (LDS reads issue before any new LDS writes)
        __builtin_amdgcn_s_setprio(1);
#pragma unroll
        for (int ks = 0; ks < 4; ++ks) {
            bf16x8 g0 = *reinterpret_cast<const bf16x8*>(&Gb[buf][ks * 2 + 0][lane * 4]);
            bf16x8 g1 = *reinterpret_cast<const bf16x8*>(&Gb[buf][ks * 2 + 1][lane * 4]);
            acc[0][0] = __builtin_amdgcn_mfma_f32_32x32x16_bf16(vreg[2 * ks],     g0, acc[0][0], 0, 0, 0);
            acc[0][1] = __builtin_amdgcn_mfma_f32_32x32x16_bf16(vreg[2 * ks],     g1, acc[0][1], 0, 0, 0);
            acc[1][0] = __builtin_amdgcn_mfma_f32_32x32x16_bf16(vreg[2 * ks + 1], g0, acc[1][0], 0, 0, 0);
            acc[1][1] = __builtin_amdgcn_mfma_f32_32x32x16_bf16(vreg[2 * ks + 1], g1, acc[1][1], 0, 0, 0);
        }
        __builtin_amdgcn_s_setprio(0);

        // (4) publish next chunk's G, rotate Wt prefetch, then barrier
        if (c < 7) store_g(buf ^ 1, dn);
        wfn = wf2;
        __syncthreads();
    }

    // ---- epilogue: D[p][sample]: col = sample; lane & lane^32 share a sample.
#pragma unroll
    for (int r2 = 0; r2 < 2; ++r2) {
        float s = 0.0f;
#pragma unroll
        for (int pt = 0; pt < 2; ++pt)
#pragma unroll
            for (int e = 0; e < 16; ++e) s += acc[pt][r2][e] * acc[pt][r2][e];
        s += __shfl_xor(s, 32);
        if (lane < 32) red[w][r2][lane] = s;
    }
    __syncthreads();

    if (tid < 64) {
        const int li = tid & 31, rr = tid >> 5;
        float q = 6.0f * (red[0][rr][li] + red[1][rr][li] + red[2][rr][li] + red[3][rr][li]);
        float n = sqrtf(q + 1e-10f);
        float d = n - KAPPA;
        float a = d * d, b = n;
#pragma unroll
        for (int m = 1; m <= 32; m <<= 1) {
            a += __shfl_xor(a, m);
            b += __shfl_xor(b, m);
        }
        if (tid == 0) {
            partials[blk]        = a;
            partials[NBLK + blk] = b;
        }
    }
}

// ---------------------------------------------------------------------------
// Kernel 3: finalize — deterministic sum of 512 per-block partials.
// ---------------------------------------------------------------------------
__global__ void finalize_k(const float* __restrict__ partials, float* __restrict__ out) {
    __shared__ float sl[256], sn[256];
    int tid = threadIdx.x;
    sl[tid] = partials[tid] + partials[tid + 256];
    sn[tid] = partials[NBLK + tid] + partials[NBLK + tid + 256];
    __syncthreads();
    for (int st = 128; st > 0; st >>= 1) {
        if (tid < st) { sl[tid] += sl[tid + st]; sn[tid] += sn[tid + st]; }
        __syncthreads();
    }
    if (tid == 0) {
        out[0] = sl[0] / 32768.0f;
        out[1] = sn[0] / 32768.0f;
    }
}

// ---------------------------------------------------------------------------
extern "C" void kernel_launch(void* const* d_in, const int* in_sizes, int n_in,
                              void* d_out, int out_size, void* d_ws, size_t ws_size,
                              hipStream_t stream) {
    const float* x  = (const float*)d_in[0];
    const float* W1 = (const float*)d_in[1];
    const float* b1 = (const float*)d_in[2];
    const float* W2 = (const float*)d_in[3];
    // b2 (d_in[4]) unused: the Jacobian kills the bias.

    bf16x8* V        = (bf16x8*)d_ws;          // 16384 frags * 16 B = 256 KB
    bf16x8* Wt       = V + 16384;              // 1024 frags * 16 B = 16 KB
    float*  partials = (float*)(Wt + 1024);    // 1024 floats

    build_v<<<68, 256, 0, stream>>>(W1, W2, b1, V, Wt);
    torsion_main<<<NBLK, 256, 0, stream>>>(x, V, Wt, partials);
    finalize_k<<<1, 256, 0, stream>>>(partials, (float*)d_out);
}